// Round 1
// 862.338 us; speedup vs baseline: 1.0819x; 1.0819x over previous
//
#include <hip/hip_runtime.h>
#include <stdint.h>

#define NFULL 1024
#define NHUB  512
#define NTOP  256
#define EFULL 523776
#define EHUB  130816
#define ETOP  32640
#define ETOT  (ETOP + EHUB + EFULL)   // 687232
#define NTOT  (NTOP + NHUB + NFULL)   // 1792
// h/xh row-buffer offsets (floats): top 256*128, hub 512*64, full 1024*64
#define HOFF_H 32768
#define HOFF_F 65536
#define HTOT   131072
#define SLOPE 0.01f

// k_ea_all: 128 edges/block, 2 threads/edge
#define NB_T2 255    // 32640/128
#define NB_H2 1022   // 130816/128
#define NB_F2 4092   // 523776/128

// k_tri_tiled: 64x64 tiles over upper-tri tile grid
#define TT_T 10      // nt=4  -> 4+3+2+1
#define TT_H 36      // nt=8
#define TT_F 136     // nt=16

__device__ __forceinline__ int trioff(int i, int n){ return (i * (2 * n - i - 1)) >> 1; }

// invT[e]=-1, invH[e]=-1 for all full edges
__global__ void k_init(int* __restrict__ invT, int* __restrict__ invH)
{
  int t = blockIdx.x * 256 + threadIdx.x;
  if (t < EFULL){ invT[t] = -1; invH[t] = -1; }
}

// scatter branch-local ids into full-edge-indexed inverse maps
__global__ void k_inv(const int* __restrict__ tmask, const int* __restrict__ hmask,
                      int* __restrict__ invT, int* __restrict__ invH)
{
  int t = blockIdx.x * 256 + threadIdx.x;
  if (t < ETOP) invT[tmask[t]] = t;
  else if (t < ETOP + EHUB) invH[hmask[t - ETOP]] = t - ETOP;
}

// ea = leaky(edge_z[ef] @ W + b) -> compact eat[ebase+t][64]; mean -> w2_all.
// 2 threads per edge (c0 = 0/32): 32 acc VGPRs/thread -> 4+ blocks/CU occupancy
// (vs previous 64-acc variant pinned at 2 blocks/CU). W staged in LDS.
__global__ __launch_bounds__(256, 4)
void k_ea_all(const float* __restrict__ ez,
              const int* __restrict__ tmask, const int* __restrict__ hmask,
              const float* __restrict__ Wt, const float* __restrict__ bt,
              const float* __restrict__ Wh, const float* __restrict__ bh,
              const float* __restrict__ Wf, const float* __restrict__ bf,
              float* __restrict__ eat, float* __restrict__ w2_all)
{
  __shared__ float sW[4096];
  __shared__ float sB[64];
  int b = blockIdx.x, tid = threadIdx.x;
  int bloc, w2off; const int* mask; const float* W; const float* bb;
  if (b < NB_T2)               { bloc = b;                 w2off = 0;           mask = tmask;   W = Wt; bb = bt; }
  else if (b < NB_T2 + NB_H2)  { bloc = b - NB_T2;         w2off = ETOP;        mask = hmask;   W = Wh; bb = bh; }
  else                         { bloc = b - NB_T2 - NB_H2; w2off = ETOP + EHUB; mask = nullptr; W = Wf; bb = bf; }
  {
    const float4* Wv = (const float4*)W;
    float4* sWv = (float4*)sW;
    #pragma unroll
    for (int q = 0; q < 4; q++) sWv[q * 256 + tid] = Wv[q * 256 + tid];
    if (tid < 64) sB[tid] = bb[tid];
  }
  __syncthreads();
  int e_loc = bloc * 128 + (tid >> 1);
  int c0 = (tid & 1) * 32;
  int ef = mask ? mask[e_loc] : e_loc;
  const float4* row4 = (const float4*)(ez + (size_t)ef * 64);

  float acc[32];
  #pragma unroll
  for (int j = 0; j < 32; j++) acc[j] = sB[c0 + j];
  #pragma unroll
  for (int k0 = 0; k0 < 64; k0 += 4){
    float4 a4 = row4[k0 >> 2];
    float av[4]; av[0]=a4.x; av[1]=a4.y; av[2]=a4.z; av[3]=a4.w;
    #pragma unroll
    for (int q = 0; q < 4; q++){
      float a = av[q];
      const float* wr = sW + (k0 + q) * 64 + c0;
      #pragma unroll
      for (int j0 = 0; j0 < 32; j0 += 4){
        float4 w4 = *(const float4*)(wr + j0);
        acc[j0+0] += a * w4.x;
        acc[j0+1] += a * w4.y;
        acc[j0+2] += a * w4.z;
        acc[j0+3] += a * w4.w;
      }
    }
  }
  float s = 0.f;
  #pragma unroll
  for (int j = 0; j < 32; j++){
    float v = acc[j];
    v = v >= 0.f ? v : SLOPE * v;
    acc[j] = v; s += v;
  }
  s += __shfl_xor(s, 1);
  if ((tid & 1) == 0) w2_all[w2off + e_loc] = s * (1.0f / 64.0f);
  float* orow = eat + (size_t)(w2off + e_loc) * 64 + c0;
  #pragma unroll
  for (int j0 = 0; j0 < 32; j0 += 4){
    float4 o; o.x = acc[j0]; o.y = acc[j0+1]; o.z = acc[j0+2]; o.w = acc[j0+3];
    *(float4*)(orow + j0) = o;
  }
}

// deg[i] = 1 + sum_j!=i w2[e(i,j)] via closed-form edge ids; dinv = rsqrt(deg)
__global__ void k_deg_all(const float* __restrict__ w2_all, float* __restrict__ dinv_all)
{
  int b = blockIdx.x, l = threadIdx.x;
  int n, i, boff; const float* w2;
  if (b < NTOP)             { n = NTOP;  i = b;               boff = 0;           w2 = w2_all; }
  else if (b < NTOP + NHUB) { n = NHUB;  i = b - NTOP;        boff = NTOP;        w2 = w2_all + ETOP; }
  else                      { n = NFULL; i = b - NTOP - NHUB; boff = NTOP + NHUB; w2 = w2_all + ETOP + EHUB; }
  float s = 0.f;
  for (int j = l; j < n; j += 64){
    if (j == i) continue;
    int e = (j < i) ? (trioff(j, n) + i - j - 1) : (trioff(i, n) + j - i - 1);
    s += w2[e];
  }
  #pragma unroll
  for (int o = 32; o > 0; o >>= 1) s += __shfl_down(s, o);
  if (l == 0){
    float deg = s + 1.0f;
    dinv_all[boff + i] = (deg > 0.f) ? rsqrtf(deg) : 0.f;
  }
}

// h = concat(node_hidden[gidx], weather) @ gW  (no bias)
__global__ void k_h_all(const float* __restrict__ nodez,
                        const float* __restrict__ wx, const float* __restrict__ hwx,
                        const float* __restrict__ twx,
                        const int* __restrict__ hidx, const int* __restrict__ tidx,
                        const float* __restrict__ gWt, const float* __restrict__ gWh,
                        const float* __restrict__ gWf,
                        float* __restrict__ h_all)
{
  int t = blockIdx.x * 256 + threadIdx.x;
  if (t >= HTOT) return;
  int i, c, gout, nrow; const float* gW; const float* wxp; const int* gidx; float* hp;
  if (t < HOFF_H)      { gout = 128; i = t / 128;  c = t & 127; gW = gWt; wxp = twx; gidx = tidx; hp = h_all; }
  else if (t < HOFF_F) { int u = t - HOFF_H; gout = 64; i = u / 64; c = u & 63; gW = gWh; wxp = hwx; gidx = hidx; hp = h_all + HOFF_H; }
  else                 { int u = t - HOFF_F; gout = 64; i = u / 64; c = u & 63; gW = gWf; wxp = wx;  gidx = nullptr; hp = h_all + HOFF_F; }
  nrow = gidx ? gidx[i] : i;
  const float* nr = nodez + (size_t)nrow * 128;
  float acc = 0.f;
  for (int k = 0; k < 128; k++) acc += nr[k] * gW[k * gout + c];
  const float* wr = wxp + (size_t)i * 16;
  for (int k = 0; k < 16; k++) acc += wr[k] * gW[(128 + k) * gout + c];
  hp[(size_t)i * gout + c] = acc;
}

// xh[i][c] = leaky( dinv[i] * sum_j coef(i,j)*dinv[j]*h[j][c] + b[c] )
__global__ void k_xh_all(const float* __restrict__ w2_all, const float* __restrict__ dinv_all,
                         const float* __restrict__ h_all,
                         const float* __restrict__ gbt, const float* __restrict__ gbh,
                         const float* __restrict__ gbf,
                         float* __restrict__ xh_all)
{
  __shared__ float part[256];
  int b = blockIdx.x, tid = threadIdx.x;
  int n, i, gout; const float* w2; const float* dinv; const float* hb; const float* gb; float* xb;
  if (b < NTOP){
    n = NTOP; i = b; gout = 128;
    w2 = w2_all; dinv = dinv_all; hb = h_all; gb = gbt; xb = xh_all;
  } else if (b < NTOP + NHUB){
    n = NHUB; i = b - NTOP; gout = 64;
    w2 = w2_all + ETOP; dinv = dinv_all + NTOP; hb = h_all + HOFF_H; gb = gbh; xb = xh_all + HOFF_H;
  } else {
    n = NFULL; i = b - NTOP - NHUB; gout = 64;
    w2 = w2_all + ETOP + EHUB; dinv = dinv_all + NTOP + NHUB; hb = h_all + HOFF_F; gb = gbf; xb = xh_all + HOFF_F;
  }
  int SJ = 256 / gout;
  int c = tid & (gout - 1);
  int js = tid / gout;
  float acc = 0.f;
  for (int j = js; j < n; j += SJ){
    float coef;
    if (j == i) coef = 1.0f;
    else {
      int e = (j < i) ? (trioff(j, n) + i - j - 1) : (trioff(i, n) + j - i - 1);
      coef = w2[e];
    }
    coef *= dinv[j];
    acc += coef * hb[(size_t)j * gout + c];
  }
  part[tid] = acc;
  __syncthreads();
  if (js == 0){
    float s = acc;
    for (int q = 1; q < SJ; q++) s += part[q * gout + c];
    s = dinv[i] * s + gb[c];
    xb[(size_t)i * gout + c] = s >= 0.f ? s : SLOPE * s;
  }
}

// tri = sigmoid(xh @ xh^T) on strict upper triangle, computed as a tiled LDS
// GEMM (adj arrays are canonical triu order -> closed-form edge ids).
// 64x64 output tile per block; each thread a 4x4 sub-tile. LDS chunks are
// XOR-swizzled (chunk ^ (row>>2 & 7)) so ds_read_b128 is <=2-way (free).
__global__ __launch_bounds__(256)
void k_tri_tiled(const float* __restrict__ xh_all, float* __restrict__ tri_all)
{
  __shared__ float sXi[8192];   // up to 64 x 128
  __shared__ float sXj[8192];
  int b = blockIdx.x, tid = threadIdx.x;
  int n, g, nt, tt, csh; const float* xb; float* tb;
  if (b < TT_T)        { n = NTOP;  g = 128; nt = 4;  csh = 5; tt = b;            xb = xh_all;          tb = tri_all; }
  else if (b < TT_T+TT_H){ n = NHUB; g = 64; nt = 8;  csh = 4; tt = b - TT_T;     xb = xh_all + HOFF_H; tb = tri_all + ETOP; }
  else                 { n = NFULL; g = 64;  nt = 16; csh = 4; tt = b - TT_T - TT_H; xb = xh_all + HOFF_F; tb = tri_all + ETOP + EHUB; }
  // tile index -> (bi, bj), bi <= bj
  int bi = 0, t = tt;
  while (t >= nt - bi){ t -= nt - bi; bi++; }
  int bj = bi + t;
  int cpr = g >> 2;           // float4 chunks per row
  int nch = 64 * cpr;
  const float* gi = xb + (size_t)(bi * 64) * g;
  const float* gj = xb + (size_t)(bj * 64) * g;
  for (int idx = tid; idx < nch; idx += 256){
    int row = idx >> csh;
    int c = idx & (cpr - 1);
    int sw = (c ^ ((row >> 2) & 7)) << 2;
    float4 v = *(const float4*)(gi + (size_t)row * g + c * 4);
    *(float4*)(sXi + row * g + sw) = v;
    float4 w = *(const float4*)(gj + (size_t)row * g + c * 4);
    *(float4*)(sXj + row * g + sw) = w;
  }
  __syncthreads();
  int ii = tid >> 4, jj = tid & 15;
  float acc[4][4];
  #pragma unroll
  for (int a = 0; a < 4; a++)
    #pragma unroll
    for (int q = 0; q < 4; q++) acc[a][q] = 0.f;
  for (int ck = 0; ck < cpr; ck++){
    int swi = (ck ^ (ii & 7)) << 2;
    int swj = (ck ^ (jj & 7)) << 2;
    float4 xi[4], xj[4];
    #pragma unroll
    for (int a = 0; a < 4; a++) xi[a] = *(const float4*)(sXi + (ii * 4 + a) * g + swi);
    #pragma unroll
    for (int q = 0; q < 4; q++) xj[q] = *(const float4*)(sXj + (jj * 4 + q) * g + swj);
    #pragma unroll
    for (int a = 0; a < 4; a++)
      #pragma unroll
      for (int q = 0; q < 4; q++){
        acc[a][q] += xi[a].x * xj[q].x;
        acc[a][q] += xi[a].y * xj[q].y;
        acc[a][q] += xi[a].z * xj[q].z;
        acc[a][q] += xi[a].w * xj[q].w;
      }
  }
  #pragma unroll
  for (int a = 0; a < 4; a++){
    int I = bi * 64 + ii * 4 + a;
    int base = trioff(I, n) - I - 1;
    #pragma unroll
    for (int q = 0; q < 4; q++){
      int J = bj * 64 + jj * 4 + q;
      if (I < J){
        float s = acc[a][q];
        tb[base + J] = 1.f / (1.f + __expf(-s));
      }
    }
  }
}

// out[e][br*64+h] = eat[ebase+eb][h] * (1 + tri*cW[h] + cb[h]) if present, else 0.
// Write-only on out (reads compact eat instead of round-tripping out).
__global__ void k_final(const float* __restrict__ eat, const float* __restrict__ tri_all,
                        const int* __restrict__ invT, const int* __restrict__ invH,
                        const float* __restrict__ cwT, const float* __restrict__ cbT,
                        const float* __restrict__ cwH, const float* __restrict__ cbH,
                        const float* __restrict__ cwF, const float* __restrict__ cbF,
                        float* __restrict__ out)
{
  __shared__ float cw[3][64], cb[3][64];
  int lt = threadIdx.x;
  if (lt < 64)       { cw[0][lt] = cwT[lt]; cb[0][lt] = cbT[lt]; }
  else if (lt < 128) { int l = lt - 64;  cw[1][l] = cwH[l]; cb[1][l] = cbH[l]; }
  else if (lt < 192) { int l = lt - 128; cw[2][l] = cwF[l]; cb[2][l] = cbF[l]; }
  __syncthreads();
  int t = blockIdx.x * 256 + threadIdx.x;
  const int TOT = EFULL * 48;
  if (t >= TOT) return;
  int e = t / 48;
  int c = t - e * 48;
  int br = c >> 4, h0 = (c & 15) * 4;
  int eb, ebase; const float* tri;
  if (br == 0)      { eb = invT[e]; tri = tri_all;               ebase = 0; }
  else if (br == 1) { eb = invH[e]; tri = tri_all + ETOP;        ebase = ETOP; }
  else              { eb = e;       tri = tri_all + ETOP + EHUB; ebase = ETOP + EHUB; }
  float* p = out + (size_t)e * 192 + br * 64 + h0;
  if (eb >= 0){
    float tv = tri[eb];
    const float* q = eat + (size_t)(ebase + eb) * 64 + h0;
    float4 v = *(const float4*)q;
    float4 o;
    o.x = v.x * (1.f + tv * cw[br][h0+0] + cb[br][h0+0]);
    o.y = v.y * (1.f + tv * cw[br][h0+1] + cb[br][h0+1]);
    o.z = v.z * (1.f + tv * cw[br][h0+2] + cb[br][h0+2]);
    o.w = v.w * (1.f + tv * cw[br][h0+3] + cb[br][h0+3]);
    *(float4*)p = o;
  } else {
    float4 z; z.x = 0.f; z.y = 0.f; z.z = 0.f; z.w = 0.f;
    *(float4*)p = z;
  }
}

extern "C" void kernel_launch(void* const* d_in, const int* in_sizes, int n_in,
                              void* d_out, int out_size, void* d_ws, size_t ws_size,
                              hipStream_t stream)
{
  const float* nodez  = (const float*)d_in[0];
  const float* wx     = (const float*)d_in[1];
  const float* hub_wx = (const float*)d_in[2];
  const float* top_wx = (const float*)d_in[3];
  const float* ez     = (const float*)d_in[4];
  const int* hidx  = (const int*)d_in[8];
  const int* tidx  = (const int*)d_in[9];
  const int* hmask = (const int*)d_in[13];
  const int* tmask = (const int*)d_in[14];
  const float* dgW_t = (const float*)d_in[15];
  const float* dgb_t = (const float*)d_in[16];
  const float* gW_t  = (const float*)d_in[17];
  const float* gb_t  = (const float*)d_in[18];
  const float* cW_t  = (const float*)d_in[19];
  const float* cb_t  = (const float*)d_in[20];
  const float* dgW_h = (const float*)d_in[21];
  const float* dgb_h = (const float*)d_in[22];
  const float* gW_h  = (const float*)d_in[23];
  const float* gb_h  = (const float*)d_in[24];
  const float* cW_h  = (const float*)d_in[25];
  const float* cb_h  = (const float*)d_in[26];
  const float* dgW_f = (const float*)d_in[27];
  const float* dgb_f = (const float*)d_in[28];
  const float* gW_f  = (const float*)d_in[29];
  const float* gb_f  = (const float*)d_in[30];
  const float* cW_f  = (const float*)d_in[31];
  const float* cb_f  = (const float*)d_in[32];

  char* w = (char*)d_ws;
  size_t off = 0;
  auto alloc = [&](size_t bytes) -> char* {
    char* p = w + off;
    off += (bytes + 255) & ~(size_t)255;
    return p;
  };
  float* w2_all   = (float*)alloc((size_t)ETOT * 4);
  float* tri_all  = (float*)alloc((size_t)ETOT * 4);
  float* dinv_all = (float*)alloc((size_t)NTOT * 4);
  float* h_all    = (float*)alloc((size_t)HTOT * 4);
  float* xh_all   = (float*)alloc((size_t)HTOT * 4);
  int* invT       = (int*)alloc((size_t)EFULL * 4);
  int* invH       = (int*)alloc((size_t)EFULL * 4);
  float* eat      = (float*)alloc((size_t)ETOT * 64 * 4);   // ~176 MB, ws is ~1.6 GB
  (void)ws_size; (void)in_sizes; (void)n_in; (void)out_size;

  float* outp = (float*)d_out;

  k_init<<<(EFULL + 255) / 256, 256, 0, stream>>>(invT, invH);
  k_inv<<<(ETOP + EHUB + 255) / 256, 256, 0, stream>>>(tmask, hmask, invT, invH);
  k_ea_all<<<NB_T2 + NB_H2 + NB_F2, 256, 0, stream>>>(ez, tmask, hmask,
      dgW_t, dgb_t, dgW_h, dgb_h, dgW_f, dgb_f, eat, w2_all);
  k_h_all<<<(HTOT + 255) / 256, 256, 0, stream>>>(nodez, wx, hub_wx, top_wx,
      hidx, tidx, gW_t, gW_h, gW_f, h_all);
  k_deg_all<<<NTOT, 64, 0, stream>>>(w2_all, dinv_all);
  k_xh_all<<<NTOT, 256, 0, stream>>>(w2_all, dinv_all, h_all, gb_t, gb_h, gb_f, xh_all);
  k_tri_tiled<<<TT_T + TT_H + TT_F, 256, 0, stream>>>(xh_all, tri_all);
  k_final<<<(EFULL * 48 + 255) / 256, 256, 0, stream>>>(
      eat, tri_all, invT, invH, cW_t, cb_t, cW_h, cb_h, cW_f, cb_f, outp);
}